// Round 7
// baseline (402.937 us; speedup 1.0000x reference)
//
#include <hip/hip_runtime.h>
#include <math.h>

#define NFAM 32
#define MREC 64
#define TSTRIDE 66                      // tile row stride: col 64 = count, 65 = pad
#define TILE_ELEMS (NFAM * TSTRIDE)     // 2112 floats = 8448 B
#define K1_BLOCKS 512
#define K1_THREADS 512                  // 8 waves/block
#define K1_WAVES 8
#define K2_BLOCKS 16

// ---------------------------------------------------------------------------
// K1: per-WAVE private LDS accumulation (no inter-wave atomic contention),
// in-block tree reduction, one plain-store partial tile per block.
// ---------------------------------------------------------------------------
__global__ __launch_bounds__(K1_THREADS) void mmi_accum(
    const float* __restrict__ activity,
    const int*   __restrict__ family_ids,
    float*       __restrict__ partial,   // [K1_BLOCKS][TILE_ELEMS]
    int n_rows)
{
    __shared__ float lds[K1_WAVES * TILE_ELEMS];   // 8 * 8448 B = 67.6 KB
    const int tid = threadIdx.x;

    for (int i = tid; i < K1_WAVES * TILE_ELEMS; i += K1_THREADS) lds[i] = 0.0f;
    __syncthreads();

    const int wave = tid >> 6;
    const int lane = tid & 63;
    const int sub  = lane >> 4;          // row within quad (0..3)
    const int c    = lane & 15;          // column-quad (cols 4c..4c+3)
    float* tile = lds + wave * TILE_ELEMS;

    const long long gw     = (long long)blockIdx.x * K1_WAVES + wave;
    const long long nwaves = (long long)gridDim.x * K1_WAVES;

    // Each wave streams contiguous 128-row chunks: 32 iterations x 4 rows.
    for (long long base = gw * 128; base < n_rows; base += nwaves * 128) {
        #pragma unroll 4
        for (int it = 0; it < 32; ++it) {
            const long long row = base + it * 4 + sub;
            if (row < n_rows) {
                const float4 v =
                    *reinterpret_cast<const float4*>(activity + row * MREC + c * 4);
                const int fam = family_ids[row];
                float* tr = tile + fam * TSTRIDE;
                // per-wave private tile: ds_add_f32, no cross-wave contention
                unsafeAtomicAdd(tr + c * 4 + 0, v.x);
                unsafeAtomicAdd(tr + c * 4 + 1, v.y);
                unsafeAtomicAdd(tr + c * 4 + 2, v.z);
                unsafeAtomicAdd(tr + c * 4 + 3, v.w);
                if (c == 0) unsafeAtomicAdd(tr + 64, 1.0f);   // count
            }
        }
    }
    __syncthreads();

    // Reduce the 8 wave tiles and store one partial tile (coalesced, no atomics).
    for (int e = tid; e < TILE_ELEMS; e += K1_THREADS) {
        float s = lds[e];
        #pragma unroll
        for (int w = 1; w < K1_WAVES; ++w) s += lds[w * TILE_ELEMS + e];
        partial[(long long)blockIdx.x * TILE_ELEMS + e] = s;
    }
}

// ---------------------------------------------------------------------------
// K2: 16 blocks reduce K1_BLOCKS partial tiles -> 16 tiles (coalesced reads).
// ---------------------------------------------------------------------------
__global__ __launch_bounds__(256) void mmi_reduce(
    const float* __restrict__ partial,   // [K1_BLOCKS][TILE_ELEMS]
    float*       __restrict__ partial2)  // [K2_BLOCKS][TILE_ELEMS]
{
    const int b = blockIdx.x;
    for (int e = threadIdx.x; e < TILE_ELEMS; e += 256) {
        float s = 0.0f;
        for (int t = b; t < K1_BLOCKS; t += K2_BLOCKS)
            s += partial[(long long)t * TILE_ELEMS + e];
        partial2[b * TILE_ELEMS + e] = s;
    }
}

// ---------------------------------------------------------------------------
// K3: final 16-way reduce + double-precision entropy difference.
//   out = h_a_given_f - h_a = Sa - Sf/nfam
// ---------------------------------------------------------------------------
__global__ __launch_bounds__(256) void mmi_finalize(
    const float* __restrict__ partial2,
    float*       __restrict__ out)
{
    __shared__ float fin[TILE_ELEMS];
    const int tid = threadIdx.x;

    for (int e = tid; e < TILE_ELEMS; e += 256) {
        float s = 0.0f;
        #pragma unroll
        for (int b = 0; b < K2_BLOCKS; ++b) s += partial2[b * TILE_ELEMS + e];
        fin[e] = s;
    }
    __syncthreads();

    if (tid < 64) {
        const int m = tid;
        double Ntot = 0.0;
        int nfam = 0;
        for (int f = 0; f < NFAM; ++f) {
            double cf = (double)fin[f * TSTRIDE + 64];
            Ntot += cf;
            nfam += (cf > 0.0);
        }

        // pooled entropy term for receptor m
        double T = 0.0;
        for (int f = 0; f < NFAM; ++f) T += (double)fin[f * TSTRIDE + m];
        double mean = T / Ntot;
        double ja = (1.0 - mean) * (1.0 - mean) + mean * mean;
        double la = log(ja);

        // per-family entropy terms for receptor m
        double lf = 0.0;
        for (int f = 0; f < NFAM; ++f) {
            double cf = (double)fin[f * TSTRIDE + 64];
            if (cf > 0.0) {
                double mf = (double)fin[f * TSTRIDE + m] / cf;
                double jf = (1.0 - mf) * (1.0 - mf) + mf * mf;
                lf += log(jf);
            }
        }

        // wave-wide (64-lane) sum reduction
        for (int off = 32; off > 0; off >>= 1) {
            la += __shfl_down(la, off, 64);
            lf += __shfl_down(lf, off, 64);
        }
        if (m == 0) out[0] = (float)(la - lf / (double)nfam);
    }
}

extern "C" void kernel_launch(void* const* d_in, const int* in_sizes, int n_in,
                              void* d_out, int out_size, void* d_ws, size_t ws_size,
                              hipStream_t stream) {
    const float* activity   = (const float*)d_in[0];
    const int*   family_ids = (const int*)d_in[1];
    float*       out        = (float*)d_out;

    const int n_rows = in_sizes[1];   // N = 524288

    float* partial  = (float*)d_ws;                                   // 4.33 MB
    float* partial2 = partial + (size_t)K1_BLOCKS * TILE_ELEMS;       // 135 KB
    // ws needed: (512+16)*2112*4 B ~= 4.46 MB; everything write-before-read,
    // so no memset required.

    mmi_accum<<<K1_BLOCKS, K1_THREADS, 0, stream>>>(activity, family_ids, partial, n_rows);
    mmi_reduce<<<K2_BLOCKS, 256, 0, stream>>>(partial, partial2);
    mmi_finalize<<<1, 256, 0, stream>>>(partial2, out);
}

// Round 10
// 279.970 us; speedup vs baseline: 1.4392x; 1.4392x over previous
//
#include <hip/hip_runtime.h>
#include <math.h>

#define NFAM 32
#define MREC 64
#define TSTRIDE 66                      // tile row stride: col 64 = count, 65 = pad
#define TILE_ELEMS (NFAM * TSTRIDE)     // 2112 floats = 8448 B
#define K1_BLOCKS 512
#define K1_THREADS 512                  // 8 waves/block
#define K1_WAVES 8
#define ROWS_PER_WAVE 128
#define K2_BLOCKS 16

// ---------------------------------------------------------------------------
// K1: NO ATOMICS. One row per wave-step: fam is wave-uniform (readlane to
// SGPR), each lane owns one column -> plain LDS read-modify-write at
// tile[fam*66 + lane], all addresses distinct. Counts via ballot into a
// per-lane register. 8 row-loads batched ahead of the RMW chain for MLP.
// ---------------------------------------------------------------------------
__global__ __launch_bounds__(K1_THREADS) void mmi_accum(
    const float* __restrict__ activity,
    const int*   __restrict__ family_ids,
    float*       __restrict__ partial,   // [K1_BLOCKS][TILE_ELEMS]
    int n_rows)
{
    __shared__ float lds[K1_WAVES * TILE_ELEMS];   // 8 * 8448 B = 67.6 KB
    const int tid = threadIdx.x;

    for (int i = tid; i < K1_WAVES * TILE_ELEMS; i += K1_THREADS) lds[i] = 0.0f;
    __syncthreads();

    const int wave = tid >> 6;
    const int lane = tid & 63;
    float* tile = lds + wave * TILE_ELEMS;
    float* acc  = tile + lane;           // this lane's column slot

    float rc = 0.0f;                     // lane f (<32) accumulates count of family f

    const long long gw = (long long)blockIdx.x * K1_WAVES + wave;
    const long long nw = (long long)gridDim.x * K1_WAVES;

    for (long long wbase = gw * ROWS_PER_WAVE; wbase < n_rows;
         wbase += nw * ROWS_PER_WAVE) {
        #pragma unroll
        for (int ch = 0; ch < ROWS_PER_WAVE / 64; ++ch) {
            const long long cb = wbase + (long long)ch * 64;
            if (cb + 64 <= n_rows) {
                // ---- fast path: full 64-row chunk ----
                const int ids = family_ids[cb + lane];           // 64 ids, one per lane
                const float* ap = activity + cb * MREC + lane;   // col 'lane'
                #pragma unroll
                for (int b = 0; b < 8; ++b) {
                    // 8 independent row-loads in flight
                    const float v0 = ap[(b * 8 + 0) * MREC];
                    const float v1 = ap[(b * 8 + 1) * MREC];
                    const float v2 = ap[(b * 8 + 2) * MREC];
                    const float v3 = ap[(b * 8 + 3) * MREC];
                    const float v4 = ap[(b * 8 + 4) * MREC];
                    const float v5 = ap[(b * 8 + 5) * MREC];
                    const float v6 = ap[(b * 8 + 6) * MREC];
                    const float v7 = ap[(b * 8 + 7) * MREC];
                    // wave-uniform fam -> SGPR; plain RMW, distinct addrs per lane
                    const int f0 = __builtin_amdgcn_readlane(ids, b * 8 + 0);
                    acc[f0 * TSTRIDE] += v0;
                    const int f1 = __builtin_amdgcn_readlane(ids, b * 8 + 1);
                    acc[f1 * TSTRIDE] += v1;
                    const int f2 = __builtin_amdgcn_readlane(ids, b * 8 + 2);
                    acc[f2 * TSTRIDE] += v2;
                    const int f3 = __builtin_amdgcn_readlane(ids, b * 8 + 3);
                    acc[f3 * TSTRIDE] += v3;
                    const int f4 = __builtin_amdgcn_readlane(ids, b * 8 + 4);
                    acc[f4 * TSTRIDE] += v4;
                    const int f5 = __builtin_amdgcn_readlane(ids, b * 8 + 5);
                    acc[f5 * TSTRIDE] += v5;
                    const int f6 = __builtin_amdgcn_readlane(ids, b * 8 + 6);
                    acc[f6 * TSTRIDE] += v6;
                    const int f7 = __builtin_amdgcn_readlane(ids, b * 8 + 7);
                    acc[f7 * TSTRIDE] += v7;
                }
                // family counts for this chunk via ballot (no atomics)
                for (int f = 0; f < NFAM; ++f) {
                    const unsigned long long m = __ballot(ids == f);
                    rc += (lane == f) ? (float)__popcll(m) : 0.0f;
                }
            } else if (cb < n_rows) {
                // ---- tail: per-row guarded (cold) ----
                for (int j = 0; j < 64; ++j) {
                    const long long row = cb + j;
                    if (row >= n_rows) break;
                    const int fam = family_ids[row];
                    const float v = activity[row * MREC + lane];
                    acc[fam * TSTRIDE] += v;
                    rc += (lane == fam) ? 1.0f : 0.0f;
                }
            }
        }
    }

    // flush per-lane counts into the tile
    if (lane < NFAM) tile[lane * TSTRIDE + 64] += rc;
    __syncthreads();

    // Reduce the 8 wave tiles and store one partial tile (coalesced, no atomics).
    for (int e = tid; e < TILE_ELEMS; e += K1_THREADS) {
        float s = lds[e];
        #pragma unroll
        for (int w = 1; w < K1_WAVES; ++w) s += lds[w * TILE_ELEMS + e];
        partial[(long long)blockIdx.x * TILE_ELEMS + e] = s;
    }
}

// ---------------------------------------------------------------------------
// K2: 16 blocks reduce K1_BLOCKS partial tiles -> 16 tiles (coalesced reads).
// ---------------------------------------------------------------------------
__global__ __launch_bounds__(256) void mmi_reduce(
    const float* __restrict__ partial,   // [K1_BLOCKS][TILE_ELEMS]
    float*       __restrict__ partial2)  // [K2_BLOCKS][TILE_ELEMS]
{
    const int b = blockIdx.x;
    for (int e = threadIdx.x; e < TILE_ELEMS; e += 256) {
        float s = 0.0f;
        for (int t = b; t < K1_BLOCKS; t += K2_BLOCKS)
            s += partial[(long long)t * TILE_ELEMS + e];
        partial2[b * TILE_ELEMS + e] = s;
    }
}

// ---------------------------------------------------------------------------
// K3: final 16-way reduce + double-precision entropy difference.
//   out = h_a_given_f - h_a = Sa - Sf/nfam
// ---------------------------------------------------------------------------
__global__ __launch_bounds__(256) void mmi_finalize(
    const float* __restrict__ partial2,
    float*       __restrict__ out)
{
    __shared__ float fin[TILE_ELEMS];
    const int tid = threadIdx.x;

    for (int e = tid; e < TILE_ELEMS; e += 256) {
        float s = 0.0f;
        #pragma unroll
        for (int b = 0; b < K2_BLOCKS; ++b) s += partial2[b * TILE_ELEMS + e];
        fin[e] = s;
    }
    __syncthreads();

    if (tid < 64) {
        const int m = tid;
        double Ntot = 0.0;
        int nfam = 0;
        for (int f = 0; f < NFAM; ++f) {
            double cf = (double)fin[f * TSTRIDE + 64];
            Ntot += cf;
            nfam += (cf > 0.0);
        }

        // pooled entropy term for receptor m
        double T = 0.0;
        for (int f = 0; f < NFAM; ++f) T += (double)fin[f * TSTRIDE + m];
        double mean = T / Ntot;
        double ja = (1.0 - mean) * (1.0 - mean) + mean * mean;
        double la = log(ja);

        // per-family entropy terms for receptor m
        double lf = 0.0;
        for (int f = 0; f < NFAM; ++f) {
            double cf = (double)fin[f * TSTRIDE + 64];
            if (cf > 0.0) {
                double mf = (double)fin[f * TSTRIDE + m] / cf;
                double jf = (1.0 - mf) * (1.0 - mf) + mf * mf;
                lf += log(jf);
            }
        }

        // wave-wide (64-lane) sum reduction
        for (int off = 32; off > 0; off >>= 1) {
            la += __shfl_down(la, off, 64);
            lf += __shfl_down(lf, off, 64);
        }
        if (m == 0) out[0] = (float)(la - lf / (double)nfam);
    }
}

extern "C" void kernel_launch(void* const* d_in, const int* in_sizes, int n_in,
                              void* d_out, int out_size, void* d_ws, size_t ws_size,
                              hipStream_t stream) {
    const float* activity   = (const float*)d_in[0];
    const int*   family_ids = (const int*)d_in[1];
    float*       out        = (float*)d_out;

    const int n_rows = in_sizes[1];   // N = 524288

    float* partial  = (float*)d_ws;                                   // 4.33 MB
    float* partial2 = partial + (size_t)K1_BLOCKS * TILE_ELEMS;       // 135 KB

    mmi_accum<<<K1_BLOCKS, K1_THREADS, 0, stream>>>(activity, family_ids, partial, n_rows);
    mmi_reduce<<<K2_BLOCKS, 256, 0, stream>>>(partial, partial2);
    mmi_finalize<<<1, 256, 0, stream>>>(partial2, out);
}